// Round 6
// baseline (693.100 us; speedup 1.0000x reference)
//
#include <hip/hip_runtime.h>

#define N_NODES 100000
#define N_EDGES 1600000
#define D 128
#define SCAN_BLOCKS 391   // ceil(N_NODES / 256)
#define NBUCK 98          // ceil(N_NODES / 1024), bucket = dst >> 10

typedef __attribute__((ext_vector_type(8))) short bf16x8;
typedef __attribute__((ext_vector_type(4))) float f32x4;
typedef unsigned long long u64;

__device__ __forceinline__ float b2f_lo(unsigned int u) {
    return __builtin_bit_cast(float, u << 16);
}
__device__ __forceinline__ float b2f_hi(unsigned int u) {
    return __builtin_bit_cast(float, u & 0xFFFF0000u);
}
__device__ __forceinline__ unsigned short f2b(float f) {
    unsigned int u = __builtin_bit_cast(unsigned int, f);
    u += 0x7FFFu + ((u >> 16) & 1u);
    return (unsigned short)(u >> 16);
}

// ---------------- CSR build ----------------

__global__ void hist_kernel(const int* __restrict__ dst, int* __restrict__ deg, int n) {
    int i = blockIdx.x * blockDim.x + threadIdx.x;
    if (i < n) atomicAdd(&deg[dst[i]], 1);
}

__global__ __launch_bounds__(256) void block_sum_kernel(const int* __restrict__ deg,
                                                        int* __restrict__ bsum) {
    __shared__ int s[256];
    int i = blockIdx.x * 256 + threadIdx.x;
    int v = (i < N_NODES) ? deg[i] : 0;
    s[threadIdx.x] = v;
    __syncthreads();
#pragma unroll
    for (int d = 128; d > 0; d >>= 1) {
        if (threadIdx.x < d) s[threadIdx.x] += s[threadIdx.x + d];
        __syncthreads();
    }
    if (threadIdx.x == 0) bsum[blockIdx.x] = s[0];
}

__global__ __launch_bounds__(512) void scan_bsum_kernel(const int* __restrict__ bsum,
                                                        int* __restrict__ bpref,
                                                        int* __restrict__ off) {
    __shared__ int s[512];
    int tid = threadIdx.x;
    int v = (tid < SCAN_BLOCKS) ? bsum[tid] : 0;
    s[tid] = v;
    __syncthreads();
#pragma unroll
    for (int d = 1; d < 512; d <<= 1) {
        int t = (tid >= d) ? s[tid - d] : 0;
        __syncthreads();
        s[tid] += t;
        __syncthreads();
    }
    if (tid < SCAN_BLOCKS) bpref[tid] = s[tid] - v;   // exclusive
    if (tid == 0) off[N_NODES] = N_EDGES;
}

__global__ __launch_bounds__(256) void block_scan_kernel(const int* __restrict__ deg,
                                                         const int* __restrict__ bpref,
                                                         int* __restrict__ off) {
    __shared__ int s[256];
    int i = blockIdx.x * 256 + threadIdx.x;
    int tid = threadIdx.x;
    int v = (i < N_NODES) ? deg[i] : 0;
    s[tid] = v;
    __syncthreads();
#pragma unroll
    for (int d = 1; d < 256; d <<= 1) {
        int t = (tid >= d) ? s[tid - d] : 0;
        __syncthreads();
        s[tid] += t;
        __syncthreads();
    }
    if (i < N_NODES) off[i] = bpref[blockIdx.x] + s[tid] - v;   // exclusive
}

// Bin edges into bucket-ordered packed (dst<<32|src) slabs. Slab base = off[b<<10].
__global__ __launch_bounds__(256) void bin_kernel(const int* __restrict__ src,
                                                  const int* __restrict__ dst,
                                                  const int* __restrict__ off,
                                                  int* __restrict__ bcur,
                                                  u64* __restrict__ ebuf) {
    __shared__ int h[NBUCK];
    __shared__ int base[NBUCK];
    int tid = threadIdx.x;
    if (tid < NBUCK) h[tid] = 0;
    __syncthreads();
    int e0 = blockIdx.x * 2048;
    int myd[8], mys[8];
#pragma unroll
    for (int i = 0; i < 8; i++) {
        int e = e0 + tid + i * 256;
        int dv = (e < N_EDGES) ? dst[e] : -1;
        myd[i] = dv;
        mys[i] = (e < N_EDGES) ? src[e] : 0;
        if (dv >= 0) atomicAdd(&h[dv >> 10], 1);
    }
    __syncthreads();
    if (tid < NBUCK) {
        int c = h[tid];
        base[tid] = (c > 0) ? (off[tid << 10] + atomicAdd(&bcur[tid], c)) : 0;
        h[tid] = 0;
    }
    __syncthreads();
#pragma unroll
    for (int i = 0; i < 8; i++) {
        int dv = myd[i];
        if (dv >= 0) {
            int b = dv >> 10;
            int p = base[b] + atomicAdd(&h[b], 1);
            ebuf[p] = ((u64)(unsigned int)dv << 32) | (unsigned int)mys[i];
        }
    }
}

__global__ __launch_bounds__(256) void scatter2_kernel(const u64* __restrict__ ebuf,
                                                       const int* __restrict__ off,
                                                       int* __restrict__ cnt,
                                                       int* __restrict__ csr) {
    int i = blockIdx.x * 256 + threadIdx.x;
    if (i < N_EDGES) {
        u64 e = ebuf[i];
        int dv = (int)(e >> 32);
        int p = off[dv] + atomicAdd(&cnt[dv], 1);
        csr[p] = (int)(e & 0xFFFFFFFFu);
    }
}

// ---------------- dtype conversion ----------------

__global__ __launch_bounds__(256) void convert_x_kernel(const float* __restrict__ x,
                                                        unsigned short* __restrict__ xb, int n4) {
    int i = blockIdx.x * 256 + threadIdx.x;
    if (i < n4) {
        float4 v = ((const float4*)x)[i];
        ushort4 o;
        o.x = f2b(v.x); o.y = f2b(v.y); o.z = f2b(v.z); o.w = f2b(v.w);
        ((ushort4*)xb)[i] = o;
    }
}

__global__ __launch_bounds__(256) void convert_w6_kernel(
    const float* __restrict__ W0, const float* __restrict__ W1_, const float* __restrict__ W2_,
    const float* __restrict__ W3, const float* __restrict__ W4, const float* __restrict__ W5,
    unsigned short* __restrict__ T0, unsigned short* __restrict__ T1_,
    unsigned short* __restrict__ T2_, unsigned short* __restrict__ T3,
    unsigned short* __restrict__ T4, unsigned short* __restrict__ T5) {
    const float* W;
    unsigned short* T;
    switch (blockIdx.y) {
        case 0: W = W0; T = T0; break;
        case 1: W = W1_; T = T1_; break;
        case 2: W = W2_; T = T2_; break;
        case 3: W = W3; T = T3; break;
        case 4: W = W4; T = T4; break;
        default: W = W5; T = T5; break;
    }
    int i = blockIdx.x * 256 + threadIdx.x;   // 0..16383
    int k = i >> 7, n = i & 127;
    T[n * 128 + k] = f2b(W[i]);
}

// ---------------- fused GIN layer: y = relu(relu((x + sum_nbr x) @ W1 + b1) @ W2 + b2) ----------------
// One kernel per layer. Each wave owns a 16-row strip end-to-end: gather-agg into LDS
// t-strip -> MFMA GEMM1 (W1t L2-resident) -> LDS u-strip -> MFMA GEMM2 -> store.
// No __syncthreads anywhere: strips are per-wave private; DS ops are same-wave ordered.
// LDS: 8704 B/wave (t-strip 4352 + u-strip 4352; rows padded to 136 shorts so the
// ds_read_b128 A-fragment reads are 2-way-conflict-only, which is free on CDNA4).

template <bool OUT_F32>
__global__ __launch_bounds__(256) void fused_gin_layer(const unsigned int* __restrict__ xin,
                                                       const int* __restrict__ off,
                                                       const int* __restrict__ csr,
                                                       const unsigned short* __restrict__ W1t,
                                                       const float* __restrict__ bias1,
                                                       const unsigned short* __restrict__ W2t,
                                                       const float* __restrict__ bias2,
                                                       void* __restrict__ out) {
    __shared__ char smem[4 * 8704];
    int tid = threadIdx.x;
    int wave = tid >> 6, lane = tid & 63;
    int quad = lane >> 4, mr = lane & 15;
    int m_base = blockIdx.x * 64 + wave * 16;

    unsigned short* tst = (unsigned short*)(smem + wave * 8704);
    unsigned short* ust = tst + 2176;   // +4352 bytes

    // ---- phase 1: aggregate 16 rows (two rows in flight -> 8 outstanding gathers) ----
    for (int rr = 0; rr < 16; rr += 2) {
        int r0 = m_base + rr;     if (r0 >= N_NODES) r0 = N_NODES - 1;
        int r1 = m_base + rr + 1; if (r1 >= N_NODES) r1 = N_NODES - 1;
        unsigned int v0 = xin[(size_t)r0 * 64 + lane];
        unsigned int v1 = xin[(size_t)r1 * 64 + lane];
        float a0x = b2f_lo(v0), a0y = b2f_hi(v0);
        float a1x = b2f_lo(v1), a1y = b2f_hi(v1);
        int k0 = off[r0], e0 = off[r0 + 1];
        int k1 = off[r1], e1 = off[r1 + 1];
        while ((k0 + 4 <= e0) && (k1 + 4 <= e1)) {
            int n00 = csr[k0], n01 = csr[k0 + 1], n02 = csr[k0 + 2], n03 = csr[k0 + 3];
            int n10 = csr[k1], n11 = csr[k1 + 1], n12 = csr[k1 + 2], n13 = csr[k1 + 3];
            unsigned int g00 = xin[(size_t)n00 * 64 + lane];
            unsigned int g01 = xin[(size_t)n01 * 64 + lane];
            unsigned int g02 = xin[(size_t)n02 * 64 + lane];
            unsigned int g03 = xin[(size_t)n03 * 64 + lane];
            unsigned int g10 = xin[(size_t)n10 * 64 + lane];
            unsigned int g11 = xin[(size_t)n11 * 64 + lane];
            unsigned int g12 = xin[(size_t)n12 * 64 + lane];
            unsigned int g13 = xin[(size_t)n13 * 64 + lane];
            a0x += b2f_lo(g00) + b2f_lo(g01) + b2f_lo(g02) + b2f_lo(g03);
            a0y += b2f_hi(g00) + b2f_hi(g01) + b2f_hi(g02) + b2f_hi(g03);
            a1x += b2f_lo(g10) + b2f_lo(g11) + b2f_lo(g12) + b2f_lo(g13);
            a1y += b2f_hi(g10) + b2f_hi(g11) + b2f_hi(g12) + b2f_hi(g13);
            k0 += 4; k1 += 4;
        }
        for (; k0 + 4 <= e0; k0 += 4) {
            int n00 = csr[k0], n01 = csr[k0 + 1], n02 = csr[k0 + 2], n03 = csr[k0 + 3];
            unsigned int g00 = xin[(size_t)n00 * 64 + lane];
            unsigned int g01 = xin[(size_t)n01 * 64 + lane];
            unsigned int g02 = xin[(size_t)n02 * 64 + lane];
            unsigned int g03 = xin[(size_t)n03 * 64 + lane];
            a0x += b2f_lo(g00) + b2f_lo(g01) + b2f_lo(g02) + b2f_lo(g03);
            a0y += b2f_hi(g00) + b2f_hi(g01) + b2f_hi(g02) + b2f_hi(g03);
        }
        for (; k1 + 4 <= e1; k1 += 4) {
            int n10 = csr[k1], n11 = csr[k1 + 1], n12 = csr[k1 + 2], n13 = csr[k1 + 3];
            unsigned int g10 = xin[(size_t)n10 * 64 + lane];
            unsigned int g11 = xin[(size_t)n11 * 64 + lane];
            unsigned int g12 = xin[(size_t)n12 * 64 + lane];
            unsigned int g13 = xin[(size_t)n13 * 64 + lane];
            a1x += b2f_lo(g10) + b2f_lo(g11) + b2f_lo(g12) + b2f_lo(g13);
            a1y += b2f_hi(g10) + b2f_hi(g11) + b2f_hi(g12) + b2f_hi(g13);
        }
        for (; k0 < e0; k0++) {
            unsigned int g = xin[(size_t)csr[k0] * 64 + lane];
            a0x += b2f_lo(g); a0y += b2f_hi(g);
        }
        for (; k1 < e1; k1++) {
            unsigned int g = xin[(size_t)csr[k1] * 64 + lane];
            a1x += b2f_lo(g); a1y += b2f_hi(g);
        }
        *(unsigned int*)&tst[rr * 136 + lane * 2] =
            (unsigned int)f2b(a0x) | ((unsigned int)f2b(a0y) << 16);
        *(unsigned int*)&tst[(rr + 1) * 136 + lane * 2] =
            (unsigned int)f2b(a1x) | ((unsigned int)f2b(a1y) << 16);
    }

    // ---- phase 2: u = relu(t @ W1 + b1) ----
    bf16x8 a[4];
#pragma unroll
    for (int kc = 0; kc < 4; kc++)
        a[kc] = *(const bf16x8*)&tst[mr * 136 + kc * 32 + quad * 8];

    f32x4 acc[8];
#pragma unroll
    for (int nt = 0; nt < 8; nt++) acc[nt] = (f32x4)0.0f;
#pragma unroll
    for (int nt = 0; nt < 8; nt++) {
        const unsigned short* wp = W1t + (size_t)(nt * 16 + mr) * D + quad * 8;
#pragma unroll
        for (int kc = 0; kc < 4; kc++) {
            bf16x8 b = *(const bf16x8*)(wp + kc * 32);
            acc[nt] = __builtin_amdgcn_mfma_f32_16x16x32_bf16(a[kc], b, acc[nt], 0, 0, 0);
        }
    }
    // C layout: col(n) = mr, row(m within strip) = quad*4 + r
#pragma unroll
    for (int nt = 0; nt < 8; nt++) {
        float bv = bias1[nt * 16 + mr];
#pragma unroll
        for (int r = 0; r < 4; r++)
            ust[(quad * 4 + r) * 136 + nt * 16 + mr] = f2b(fmaxf(acc[nt][r] + bv, 0.0f));
    }

    // ---- phase 3: y = relu(u @ W2 + b2) ----
#pragma unroll
    for (int kc = 0; kc < 4; kc++)
        a[kc] = *(const bf16x8*)&ust[mr * 136 + kc * 32 + quad * 8];
#pragma unroll
    for (int nt = 0; nt < 8; nt++) acc[nt] = (f32x4)0.0f;
#pragma unroll
    for (int nt = 0; nt < 8; nt++) {
        const unsigned short* wp = W2t + (size_t)(nt * 16 + mr) * D + quad * 8;
#pragma unroll
        for (int kc = 0; kc < 4; kc++) {
            bf16x8 b = *(const bf16x8*)(wp + kc * 32);
            acc[nt] = __builtin_amdgcn_mfma_f32_16x16x32_bf16(a[kc], b, acc[nt], 0, 0, 0);
        }
    }

    // ---- epilogue: stage per-wave strip in LDS, coalesced store ----
    if (OUT_F32) {
        float* st = (float*)tst;   // 16 x 132 f32 = 8448 B, spans t-strip + u-strip
        const int S = 132;
#pragma unroll
        for (int nt = 0; nt < 8; nt++) {
            float bv = bias2[nt * 16 + mr];
#pragma unroll
            for (int r = 0; r < 4; r++)
                st[(quad * 4 + r) * S + nt * 16 + mr] = fmaxf(acc[nt][r] + bv, 0.0f);
        }
        float* op = (float*)out;
#pragma unroll
        for (int it = 0; it < 8; it++) {
            int linear = lane + it * 64;
            int row = linear >> 5, col = (linear & 31) << 2;
            int gm = m_base + row;
            if (gm < N_NODES) {
                float4 val = *(float4*)&st[row * S + col];
                *(float4*)(op + (size_t)gm * D + col) = val;
            }
        }
    } else {
        unsigned short* st = tst;  // 16 x 136 bf16 = 4352 B (t-strip only)
        const int S = 136;
#pragma unroll
        for (int nt = 0; nt < 8; nt++) {
            float bv = bias2[nt * 16 + mr];
#pragma unroll
            for (int r = 0; r < 4; r++)
                st[(quad * 4 + r) * S + nt * 16 + mr] = f2b(fmaxf(acc[nt][r] + bv, 0.0f));
        }
        unsigned short* op = (unsigned short*)out;
#pragma unroll
        for (int it = 0; it < 4; it++) {
            int linear = lane + it * 64;
            int row = linear >> 4, col = (linear & 15) << 3;
            int gm = m_base + row;
            if (gm < N_NODES) {
                uint4 val = *(uint4*)&st[row * S + col];
                *(uint4*)(op + (size_t)gm * D + col) = val;
            }
        }
    }
}

// ---------------- launch ----------------

extern "C" void kernel_launch(void* const* d_in, const int* in_sizes, int n_in,
                              void* d_out, int out_size, void* d_ws, size_t ws_size,
                              hipStream_t stream) {
    const float* x = (const float*)d_in[0];
    const int* ei = (const int*)d_in[1];
    const int* srcv = ei;
    const int* dstv = ei + N_EDGES;
    const float* W1[3] = {(const float*)d_in[2], (const float*)d_in[6], (const float*)d_in[10]};
    const float* b1[3] = {(const float*)d_in[3], (const float*)d_in[7], (const float*)d_in[11]};
    const float* W2[3] = {(const float*)d_in[4], (const float*)d_in[8], (const float*)d_in[12]};
    const float* b2[3] = {(const float*)d_in[5], (const float*)d_in[9], (const float*)d_in[13]};

    char* ws = (char*)d_ws;
    int* off = (int*)ws;                               // (N+1) ints
    int* deg = (int*)(ws + 400128);                    // N ints (degree, then scatter cursor)
    int* csr = (int*)(ws + 800256);                    // E ints (ends 7200256)
    unsigned short* xb = (unsigned short*)(ws + 7200256);   // N*D bf16 (ends 32800256)
    unsigned short* P  = (unsigned short*)(ws + 32800256);  // N*D bf16 (ends 58400256)
    u64* ebuf = (u64*)(ws + 7200256);                  // E u64 overlays xb (dead until convert_x)
    char* dob = (char*)d_out;
    int* bcur  = (int*)(dob + 0);
    int* bsum  = (int*)(dob + 2048);
    int* bpref = (int*)(dob + 4096);
    unsigned short* Wt[6];
    for (int i = 0; i < 6; i++) Wt[i] = (unsigned short*)(ws + 400128 + i * 32768);

    // --- CSR build (once; reused by all 3 layers) ---
    hipMemsetAsync(dob, 0, 8192, stream);
    hipMemsetAsync(deg, 0, (size_t)N_NODES * 4, stream);
    hist_kernel<<<(N_EDGES + 255) / 256, 256, 0, stream>>>(dstv, deg, N_EDGES);
    block_sum_kernel<<<SCAN_BLOCKS, 256, 0, stream>>>(deg, bsum);
    scan_bsum_kernel<<<1, 512, 0, stream>>>(bsum, bpref, off);
    block_scan_kernel<<<SCAN_BLOCKS, 256, 0, stream>>>(deg, bpref, off);
    bin_kernel<<<782, 256, 0, stream>>>(srcv, dstv, off, bcur, ebuf);
    hipMemsetAsync(deg, 0, (size_t)N_NODES * 4, stream);
    scatter2_kernel<<<(N_EDGES + 255) / 256, 256, 0, stream>>>(ebuf, off, deg, csr);

    // --- dtype conversions (deg + ebuf dead now) ---
    convert_w6_kernel<<<dim3(64, 6), 256, 0, stream>>>(
        W1[0], W2[0], W1[1], W2[1], W1[2], W2[2],
        Wt[0], Wt[1], Wt[2], Wt[3], Wt[4], Wt[5]);
    convert_x_kernel<<<(3200000 + 255) / 256, 256, 0, stream>>>(x, xb, 3200000);

    const int grid = (N_NODES + 63) / 64;              // 1563 blocks, 4 waves each

    fused_gin_layer<false><<<grid, 256, 0, stream>>>((const unsigned int*)xb, off, csr,
                                                     Wt[0], b1[0], Wt[1], b2[0], P);
    fused_gin_layer<false><<<grid, 256, 0, stream>>>((const unsigned int*)P, off, csr,
                                                     Wt[2], b1[1], Wt[3], b2[1], xb);
    fused_gin_layer<true><<<grid, 256, 0, stream>>>((const unsigned int*)xb, off, csr,
                                                    Wt[4], b1[2], Wt[5], b2[2], d_out);
}

// Round 7
// 669.681 us; speedup vs baseline: 1.0350x; 1.0350x over previous
//
#include <hip/hip_runtime.h>

#define N_NODES 100000
#define N_EDGES 1600000
#define D 128
#define SCAN_BLOCKS 391   // ceil(N_NODES / 256)
#define NBUCK 98          // ceil(N_NODES / 1024), bucket = dst >> 10

typedef __attribute__((ext_vector_type(8))) short bf16x8;
typedef __attribute__((ext_vector_type(4))) float f32x4;
typedef unsigned long long u64;

__device__ __forceinline__ float b2f_lo(unsigned int u) {
    return __builtin_bit_cast(float, u << 16);
}
__device__ __forceinline__ float b2f_hi(unsigned int u) {
    return __builtin_bit_cast(float, u & 0xFFFF0000u);
}
__device__ __forceinline__ unsigned short f2b(float f) {
    unsigned int u = __builtin_bit_cast(unsigned int, f);
    u += 0x7FFFu + ((u >> 16) & 1u);
    return (unsigned short)(u >> 16);
}

// ---------------- single zero kernel (replaces 3 hipMemsetAsync dispatches) ----------------
// zeros: deg (25008 uint4), cnt2 (25008 uint4), d_out counter head (512 uint4)

__global__ __launch_bounds__(256) void zero_kernel(uint4* __restrict__ deg4,
                                                   uint4* __restrict__ cnt4,
                                                   uint4* __restrict__ dob4) {
    int i = blockIdx.x * 256 + threadIdx.x;
    uint4 z = {0u, 0u, 0u, 0u};
    if (i < 25008) deg4[i] = z;
    else if (i < 50016) cnt4[i - 25008] = z;
    else if (i < 50528) dob4[i - 50016] = z;
}

// ---------------- CSR build ----------------

__global__ void hist_kernel(const int* __restrict__ dst, int* __restrict__ deg, int n) {
    int i = blockIdx.x * blockDim.x + threadIdx.x;
    if (i < n) atomicAdd(&deg[dst[i]], 1);
}

__global__ __launch_bounds__(256) void block_sum_kernel(const int* __restrict__ deg,
                                                        int* __restrict__ bsum) {
    __shared__ int s[256];
    int i = blockIdx.x * 256 + threadIdx.x;
    int v = (i < N_NODES) ? deg[i] : 0;
    s[threadIdx.x] = v;
    __syncthreads();
#pragma unroll
    for (int d = 128; d > 0; d >>= 1) {
        if (threadIdx.x < d) s[threadIdx.x] += s[threadIdx.x + d];
        __syncthreads();
    }
    if (threadIdx.x == 0) bsum[blockIdx.x] = s[0];
}

__global__ __launch_bounds__(512) void scan_bsum_kernel(const int* __restrict__ bsum,
                                                        int* __restrict__ bpref,
                                                        int* __restrict__ off) {
    __shared__ int s[512];
    int tid = threadIdx.x;
    int v = (tid < SCAN_BLOCKS) ? bsum[tid] : 0;
    s[tid] = v;
    __syncthreads();
#pragma unroll
    for (int d = 1; d < 512; d <<= 1) {
        int t = (tid >= d) ? s[tid - d] : 0;
        __syncthreads();
        s[tid] += t;
        __syncthreads();
    }
    if (tid < SCAN_BLOCKS) bpref[tid] = s[tid] - v;   // exclusive
    if (tid == 0) off[N_NODES] = N_EDGES;
}

__global__ __launch_bounds__(256) void block_scan_kernel(const int* __restrict__ deg,
                                                         const int* __restrict__ bpref,
                                                         int* __restrict__ off) {
    __shared__ int s[256];
    int i = blockIdx.x * 256 + threadIdx.x;
    int tid = threadIdx.x;
    int v = (i < N_NODES) ? deg[i] : 0;
    s[tid] = v;
    __syncthreads();
#pragma unroll
    for (int d = 1; d < 256; d <<= 1) {
        int t = (tid >= d) ? s[tid - d] : 0;
        __syncthreads();
        s[tid] += t;
        __syncthreads();
    }
    if (i < N_NODES) off[i] = bpref[blockIdx.x] + s[tid] - v;   // exclusive
}

// Bin edges into bucket-ordered packed (dst<<32|src) slabs. Slab base = off[b<<10].
__global__ __launch_bounds__(256) void bin_kernel(const int* __restrict__ src,
                                                  const int* __restrict__ dst,
                                                  const int* __restrict__ off,
                                                  int* __restrict__ bcur,
                                                  u64* __restrict__ ebuf) {
    __shared__ int h[NBUCK];
    __shared__ int base[NBUCK];
    int tid = threadIdx.x;
    if (tid < NBUCK) h[tid] = 0;
    __syncthreads();
    int e0 = blockIdx.x * 2048;
    int myd[8], mys[8];
#pragma unroll
    for (int i = 0; i < 8; i++) {
        int e = e0 + tid + i * 256;
        int dv = (e < N_EDGES) ? dst[e] : -1;
        myd[i] = dv;
        mys[i] = (e < N_EDGES) ? src[e] : 0;
        if (dv >= 0) atomicAdd(&h[dv >> 10], 1);
    }
    __syncthreads();
    if (tid < NBUCK) {
        int c = h[tid];
        base[tid] = (c > 0) ? (off[tid << 10] + atomicAdd(&bcur[tid], c)) : 0;
        h[tid] = 0;
    }
    __syncthreads();
#pragma unroll
    for (int i = 0; i < 8; i++) {
        int dv = myd[i];
        if (dv >= 0) {
            int b = dv >> 10;
            int p = base[b] + atomicAdd(&h[b], 1);
            ebuf[p] = ((u64)(unsigned int)dv << 32) | (unsigned int)mys[i];
        }
    }
}

__global__ __launch_bounds__(256) void scatter2_kernel(const u64* __restrict__ ebuf,
                                                       const int* __restrict__ off,
                                                       int* __restrict__ cnt,
                                                       int* __restrict__ csr) {
    int i = blockIdx.x * 256 + threadIdx.x;
    if (i < N_EDGES) {
        u64 e = ebuf[i];
        int dv = (int)(e >> 32);
        int p = off[dv] + atomicAdd(&cnt[dv], 1);
        csr[p] = (int)(e & 0xFFFFFFFFu);
    }
}

// ---------------- fused dtype conversion (weights + x in one dispatch) ----------------

__global__ __launch_bounds__(256) void convert_all_kernel(
    const float* __restrict__ x, unsigned short* __restrict__ xb,
    const float* __restrict__ W0, const float* __restrict__ W1_, const float* __restrict__ W2_,
    const float* __restrict__ W3, const float* __restrict__ W4, const float* __restrict__ W5,
    unsigned short* __restrict__ T0, unsigned short* __restrict__ T1_,
    unsigned short* __restrict__ T2_, unsigned short* __restrict__ T3,
    unsigned short* __restrict__ T4, unsigned short* __restrict__ T5) {
    int blk = blockIdx.x;
    if (blk < 384) {
        const float* W;
        unsigned short* T;
        switch (blk >> 6) {
            case 0: W = W0; T = T0; break;
            case 1: W = W1_; T = T1_; break;
            case 2: W = W2_; T = T2_; break;
            case 3: W = W3; T = T3; break;
            case 4: W = W4; T = T4; break;
            default: W = W5; T = T5; break;
        }
        int i = (blk & 63) * 256 + threadIdx.x;   // 0..16383
        int k = i >> 7, n = i & 127;
        T[n * 128 + k] = f2b(W[i]);               // [k][n] fp32 -> [n][k] bf16
    } else {
        int i = (blk - 384) * 256 + threadIdx.x;  // float4 chunks, 3200000 total
        if (i < 3200000) {
            float4 v = ((const float4*)x)[i];
            ushort4 o;
            o.x = f2b(v.x); o.y = f2b(v.y); o.z = f2b(v.z); o.w = f2b(v.w);
            ((ushort4*)xb)[i] = o;
        }
    }
}

// ---------------- aggregation: t[i] = x[i] + sum_{j in N_in(i)} x[j]  (bf16 in/out) ----------------
// R5 form: 4 waves/block, one node per wave, high occupancy, 3.1 TB/s gather.

__global__ __launch_bounds__(256) void agg_bf16(const unsigned int* __restrict__ xb,
                                                const int* __restrict__ off,
                                                const int* __restrict__ csr,
                                                unsigned int* __restrict__ t) {
    int node = blockIdx.x * 4 + (threadIdx.x >> 6);
    if (node >= N_NODES) return;
    int lane = threadIdx.x & 63;
    unsigned int v = xb[(size_t)node * 64 + lane];
    float ax = b2f_lo(v), ay = b2f_hi(v);
    int e = off[node + 1];
    int k = off[node];
    for (; k + 4 <= e; k += 4) {
        int n0 = csr[k + 0], n1 = csr[k + 1], n2 = csr[k + 2], n3 = csr[k + 3];
        unsigned int g0 = xb[(size_t)n0 * 64 + lane];
        unsigned int g1 = xb[(size_t)n1 * 64 + lane];
        unsigned int g2 = xb[(size_t)n2 * 64 + lane];
        unsigned int g3 = xb[(size_t)n3 * 64 + lane];
        ax += b2f_lo(g0) + b2f_lo(g1) + b2f_lo(g2) + b2f_lo(g3);
        ay += b2f_hi(g0) + b2f_hi(g1) + b2f_hi(g2) + b2f_hi(g3);
    }
    for (; k < e; k++) {
        unsigned int g = xb[(size_t)csr[k] * 64 + lane];
        ax += b2f_lo(g);
        ay += b2f_hi(g);
    }
    t[(size_t)node * 64 + lane] = (unsigned int)f2b(ax) | ((unsigned int)f2b(ay) << 16);
}

// ---------------- fused MLP: y = relu(relu(t @ W1 + b1) @ W2 + b2) ----------------
// Per-wave 16-row strip, zero __syncthreads. A1 frags direct from global t; GEMM1 ->
// LDS u-strip -> A2 frags -> GEMM2 -> LDS-staged coalesced store. Saves the u
// round-trip (51 MB/layer) vs separate GEMMs. LDS/wave: 4352 B (bf16 out, epilogue
// reuses u-strip) or 8448 B (f32 out) -> 9 resp. 4 blocks/CU.

template <bool OUT_F32>
__global__ __launch_bounds__(256) void mlp_mfma(const unsigned short* __restrict__ A,
                                                const unsigned short* __restrict__ W1t,
                                                const float* __restrict__ bias1,
                                                const unsigned short* __restrict__ W2t,
                                                const float* __restrict__ bias2,
                                                void* __restrict__ out) {
    constexpr int WB = OUT_F32 ? 8448 : 4352;
    __shared__ char smem[4 * WB];
    int tid = threadIdx.x;
    int wave = tid >> 6, lane = tid & 63;
    int quad = lane >> 4, mr = lane & 15;
    int m_base = blockIdx.x * 64 + wave * 16;
    int m = m_base + mr;
    if (m >= N_NODES) m = N_NODES - 1;

    unsigned short* ust = (unsigned short*)(smem + wave * WB);   // 16 x 136 shorts

    // ---- GEMM1: u = relu(t @ W1 + b1) ----
    bf16x8 a[4];
#pragma unroll
    for (int kc = 0; kc < 4; kc++)
        a[kc] = *(const bf16x8*)(A + (size_t)m * D + kc * 32 + quad * 8);

    f32x4 acc[8];
#pragma unroll
    for (int nt = 0; nt < 8; nt++) acc[nt] = (f32x4)0.0f;
#pragma unroll
    for (int nt = 0; nt < 8; nt++) {
        const unsigned short* wp = W1t + (size_t)(nt * 16 + mr) * D + quad * 8;
#pragma unroll
        for (int kc = 0; kc < 4; kc++) {
            bf16x8 b = *(const bf16x8*)(wp + kc * 32);
            acc[nt] = __builtin_amdgcn_mfma_f32_16x16x32_bf16(a[kc], b, acc[nt], 0, 0, 0);
        }
    }
    // C layout: col(n) = mr, row(m in strip) = quad*4 + r
#pragma unroll
    for (int nt = 0; nt < 8; nt++) {
        float bv = bias1[nt * 16 + mr];
#pragma unroll
        for (int r = 0; r < 4; r++)
            ust[(quad * 4 + r) * 136 + nt * 16 + mr] = f2b(fmaxf(acc[nt][r] + bv, 0.0f));
    }

    // ---- GEMM2: y = relu(u @ W2 + b2) ----
#pragma unroll
    for (int kc = 0; kc < 4; kc++)
        a[kc] = *(const bf16x8*)&ust[mr * 136 + kc * 32 + quad * 8];
#pragma unroll
    for (int nt = 0; nt < 8; nt++) acc[nt] = (f32x4)0.0f;
#pragma unroll
    for (int nt = 0; nt < 8; nt++) {
        const unsigned short* wp = W2t + (size_t)(nt * 16 + mr) * D + quad * 8;
#pragma unroll
        for (int kc = 0; kc < 4; kc++) {
            bf16x8 b = *(const bf16x8*)(wp + kc * 32);
            acc[nt] = __builtin_amdgcn_mfma_f32_16x16x32_bf16(a[kc], b, acc[nt], 0, 0, 0);
        }
    }

    // ---- epilogue: stage strip in LDS, coalesced store ----
    if (OUT_F32) {
        float* st = (float*)ust;   // 16 x 132 f32 = 8448 B
        const int S = 132;
#pragma unroll
        for (int nt = 0; nt < 8; nt++) {
            float bv = bias2[nt * 16 + mr];
#pragma unroll
            for (int r = 0; r < 4; r++)
                st[(quad * 4 + r) * S + nt * 16 + mr] = fmaxf(acc[nt][r] + bv, 0.0f);
        }
        float* op = (float*)out;
#pragma unroll
        for (int it = 0; it < 8; it++) {
            int linear = lane + it * 64;
            int row = linear >> 5, col = (linear & 31) << 2;
            int gm = m_base + row;
            if (gm < N_NODES) {
                float4 val = *(float4*)&st[row * S + col];
                *(float4*)(op + (size_t)gm * D + col) = val;
            }
        }
    } else {
        unsigned short* st = ust;  // reuse u-strip (A2 frags consumed before overwrite)
        const int S = 136;
#pragma unroll
        for (int nt = 0; nt < 8; nt++) {
            float bv = bias2[nt * 16 + mr];
#pragma unroll
            for (int r = 0; r < 4; r++)
                st[(quad * 4 + r) * S + nt * 16 + mr] = f2b(fmaxf(acc[nt][r] + bv, 0.0f));
        }
        unsigned short* op = (unsigned short*)out;
#pragma unroll
        for (int it = 0; it < 4; it++) {
            int linear = lane + it * 64;
            int row = linear >> 4, col = (linear & 15) << 3;
            int gm = m_base + row;
            if (gm < N_NODES) {
                uint4 val = *(uint4*)&st[row * S + col];
                *(uint4*)(op + (size_t)gm * D + col) = val;
            }
        }
    }
}

// ---------------- launch ----------------

extern "C" void kernel_launch(void* const* d_in, const int* in_sizes, int n_in,
                              void* d_out, int out_size, void* d_ws, size_t ws_size,
                              hipStream_t stream) {
    const float* x = (const float*)d_in[0];
    const int* ei = (const int*)d_in[1];
    const int* srcv = ei;
    const int* dstv = ei + N_EDGES;
    const float* W1[3] = {(const float*)d_in[2], (const float*)d_in[6], (const float*)d_in[10]};
    const float* b1[3] = {(const float*)d_in[3], (const float*)d_in[7], (const float*)d_in[11]};
    const float* W2[3] = {(const float*)d_in[4], (const float*)d_in[8], (const float*)d_in[12]};
    const float* b2[3] = {(const float*)d_in[5], (const float*)d_in[9], (const float*)d_in[13]};

    char* ws = (char*)d_ws;
    int* off = (int*)ws;                               // (N+1) ints
    int* deg = (int*)(ws + 400128);                    // N ints (dead after block_scan)
    int* csr = (int*)(ws + 800256);                    // E ints (ends 7200256)
    unsigned short* xb = (unsigned short*)(ws + 7200256);   // N*D bf16 (ends 32800256)
    unsigned short* P  = (unsigned short*)(ws + 32800256);  // N*D bf16 (ends 58400256)
    u64* ebuf = (u64*)(ws + 7200256);                  // E u64 = 12.8MB, overlays xb front
    int* cnt2 = (int*)(ws + 20000256);                 // N ints, overlays xb tail (dead w/ ebuf)
    char* dob = (char*)d_out;
    int* bcur  = (int*)(dob + 0);
    int* bsum  = (int*)(dob + 2048);
    int* bpref = (int*)(dob + 4096);
    unsigned short* Wt[6];
    for (int i = 0; i < 6; i++) Wt[i] = (unsigned short*)(ws + 400128 + i * 32768);

    // --- CSR build (once; reused by all 3 layers) ---
    zero_kernel<<<198, 256, 0, stream>>>((uint4*)deg, (uint4*)cnt2, (uint4*)dob);
    hist_kernel<<<(N_EDGES + 255) / 256, 256, 0, stream>>>(dstv, deg, N_EDGES);
    block_sum_kernel<<<SCAN_BLOCKS, 256, 0, stream>>>(deg, bsum);
    scan_bsum_kernel<<<1, 512, 0, stream>>>(bsum, bpref, off);
    block_scan_kernel<<<SCAN_BLOCKS, 256, 0, stream>>>(deg, bpref, off);
    bin_kernel<<<782, 256, 0, stream>>>(srcv, dstv, off, bcur, ebuf);
    scatter2_kernel<<<(N_EDGES + 255) / 256, 256, 0, stream>>>(ebuf, off, cnt2, csr);

    // --- dtype conversions (deg + ebuf + cnt2 dead now) ---
    convert_all_kernel<<<384 + 12500, 256, 0, stream>>>(
        x, xb,
        W1[0], W2[0], W1[1], W2[1], W1[2], W2[2],
        Wt[0], Wt[1], Wt[2], Wt[3], Wt[4], Wt[5]);

    const int agg_grid = 25000;                        // 4 nodes/block
    const int mlp_grid = (N_NODES + 63) / 64;          // 1563

    // layer 0: agg xb->P, mlp P->xb
    agg_bf16<<<agg_grid, 256, 0, stream>>>((const unsigned int*)xb, off, csr, (unsigned int*)P);
    mlp_mfma<false><<<mlp_grid, 256, 0, stream>>>(P, Wt[0], b1[0], Wt[1], b2[0], xb);
    // layer 1
    agg_bf16<<<agg_grid, 256, 0, stream>>>((const unsigned int*)xb, off, csr, (unsigned int*)P);
    mlp_mfma<false><<<mlp_grid, 256, 0, stream>>>(P, Wt[2], b1[1], Wt[3], b2[1], xb);
    // layer 2
    agg_bf16<<<agg_grid, 256, 0, stream>>>((const unsigned int*)xb, off, csr, (unsigned int*)P);
    mlp_mfma<true><<<mlp_grid, 256, 0, stream>>>(P, Wt[4], b1[2], Wt[5], b2[2], d_out);
}